// Round 1
// baseline (503.730 us; speedup 1.0000x reference)
//
#include <hip/hip_runtime.h>
#include <math.h>

// TopKRouter: logits = rf @ gw^T, softmax, top-2, aux load-balance loss.
// rf: [16384, 4096] f32, gw: [64, 4096] f32.
// out (f32 flat): weights [0,32768) | indices-as-float [32768,65536) | aux [65536]

constexpr int B_ROWS = 16384;
constexpr int D_DIM  = 4096;
constexpr int E_EXP  = 64;
constexpr int BD     = 128;   // d-chunk per staging iteration
constexpr int TM     = 64;    // rows per block (= wavefront size, lane = row)
constexpr int NTHR   = 512;   // 8 waves; wave w owns experts 8w..8w+7
constexpr int NWAVE  = NTHR / 64;

__device__ __forceinline__ float wave_max64(float v) {
#pragma unroll
  for (int m = 32; m >= 1; m >>= 1) v = fmaxf(v, __shfl_xor(v, m, 64));
  return v;
}

__device__ __forceinline__ float wave_sum64(float v) {
#pragma unroll
  for (int m = 32; m >= 1; m >>= 1) v += __shfl_xor(v, m, 64);
  return v;
}

// argmax over 64 lanes; ties -> smaller index (matches jax.lax.top_k stability)
__device__ __forceinline__ void wave_argmax64(float v, int i, float& mv, int& mi) {
#pragma unroll
  for (int m = 32; m >= 1; m >>= 1) {
    float ov = __shfl_xor(v, m, 64);
    int   oi = __shfl_xor(i, m, 64);
    if (ov > v || (ov == v && oi < i)) { v = ov; i = oi; }
  }
  mv = v; mi = i;
}

__global__ __launch_bounds__(NTHR, 2) void router_fused(
    const float* __restrict__ rf, const float* __restrict__ gw,
    float* __restrict__ out, float* __restrict__ psum,
    unsigned int* __restrict__ cnt) {
  // rf tile, XOR-swizzled so compute-phase ds_read_b128 spreads 8 words/bank
  __shared__ float lds[TM * BD];               // 32 KB
  __shared__ float lt[TM * (E_EXP + 1)];       // logits tile, +1 pad
  __shared__ unsigned int scnt[E_EXP];
  __shared__ float sP[NWAVE][E_EXP];

  const int t    = threadIdx.x;
  const int wv   = __builtin_amdgcn_readfirstlane(t >> 6);
  const int lane = t & 63;                     // = row within tile
  const int row0 = blockIdx.x * TM;
  const int e0   = wv * 8;
  const int srz  = 4 * (lane & 15);            // read-side swizzle for my row

  if (t < E_EXP) scnt[t] = 0;

  float acc[8] = {0.f, 0.f, 0.f, 0.f, 0.f, 0.f, 0.f, 0.f};
  const float* wb = gw + (size_t)e0 * D_DIM;   // wave-uniform base

  for (int c0 = 0; c0 < D_DIM; c0 += BD) {
    __syncthreads();  // protect LDS against waves still reading previous tile
    // stage 64 rows x 128 cols: 2048 float4s across 512 threads (4 each)
#pragma unroll
    for (int j = 0; j < 4; ++j) {
      int q  = j * NTHR + t;       // quad index 0..2047
      int r  = q >> 5;             // 32 quads per row
      int dc = (q & 31) * 4;       // logical column within chunk
      float4 v = *(const float4*)(rf + (size_t)(row0 + r) * D_DIM + c0 + dc);
      *(float4*)(lds + r * BD + (dc ^ (4 * (r & 15)))) = v;
    }
    __syncthreads();
    // compute: lane r, 8 experts; a from LDS, w wave-uniform (s_load-able)
#pragma unroll 8
    for (int k = 0; k < BD / 4; ++k) {
      float4 a = *(const float4*)(lds + lane * BD + ((4 * k) ^ srz));
      const float* wc = wb + c0 + 4 * k;
#pragma unroll
      for (int e = 0; e < 8; ++e) {
        float4 w4 = *(const float4*)(wc + (size_t)e * D_DIM);
        acc[e] = fmaf(a.x, w4.x, acc[e]);
        acc[e] = fmaf(a.y, w4.y, acc[e]);
        acc[e] = fmaf(a.z, w4.z, acc[e]);
        acc[e] = fmaf(a.w, w4.w, acc[e]);
      }
    }
  }

  // scatter logits into padded LDS tile: lt[row][expert]
#pragma unroll
  for (int e = 0; e < 8; ++e) lt[lane * (E_EXP + 1) + e0 + e] = acc[e];
  __syncthreads();

  // stats phase: wave wv handles rows 8*wv..8*wv+7; lane = expert index
  float Pacc = 0.f;
#pragma unroll
  for (int j = 0; j < 8; ++j) {
    const int r = wv * 8 + j;
    const float l = lt[r * (E_EXP + 1) + lane];
    // full softmax prob for P-mean
    const float m = wave_max64(l);
    const float p = __expf(l - m);
    const float s = wave_sum64(p);
    Pacc += p / s;
    // top-2
    float v1; int i1;
    wave_argmax64(l, lane, v1, i1);
    const float lm = (lane == i1) ? -INFINITY : l;
    float v2; int i2;
    wave_argmax64(lm, lane, v2, i2);
    if (lane == 0) {
      const float ex = expf(v2 - v1);   // v2 <= v1, stable
      const float w1 = 1.f / (1.f + ex);
      const float w2 = ex / (1.f + ex);
      const int row = row0 + r;
      out[row * 2 + 0] = w1;
      out[row * 2 + 1] = w2;
      out[2 * B_ROWS + row * 2 + 0] = (float)i1;
      out[2 * B_ROWS + row * 2 + 1] = (float)i2;
      atomicAdd(&scnt[i1], 1u);
      atomicAdd(&scnt[i2], 1u);
    }
  }
  sP[wv][lane] = Pacc;
  __syncthreads();
  if (t < E_EXP) {
    float tot = 0.f;
#pragma unroll
    for (int w = 0; w < NWAVE; ++w) tot += sP[w][t];
    atomicAdd(&psum[t], tot);
    atomicAdd(&cnt[t], scnt[t]);
  }
}

__global__ void aux_finalize(const float* __restrict__ psum,
                             const unsigned int* __restrict__ cnt,
                             float* __restrict__ out) {
  const int t = threadIdx.x;  // 64 threads
  const float f = (float)cnt[t] / (float)(B_ROWS * 2);
  const float P = psum[t] / (float)B_ROWS;
  float v = f * P;
  v = wave_sum64(v);
  if (t == 0) out[4 * B_ROWS] = (float)E_EXP * v;
}

extern "C" void kernel_launch(void* const* d_in, const int* in_sizes, int n_in,
                              void* d_out, int out_size, void* d_ws, size_t ws_size,
                              hipStream_t stream) {
  const float* rf = (const float*)d_in[0];
  const float* gw = (const float*)d_in[1];
  float* out = (float*)d_out;
  float* psum = (float*)d_ws;
  unsigned int* cnt = (unsigned int*)((char*)d_ws + 256);

  hipMemsetAsync(d_ws, 0, 512, stream);
  router_fused<<<B_ROWS / TM, NTHR, 0, stream>>>(rf, gw, out, psum, cnt);
  aux_finalize<<<1, 64, 0, stream>>>(psum, cnt, out);
}